// Round 7
// baseline (140.393 us; speedup 1.0000x reference)
//
#include <hip/hip_runtime.h>
#include <hip/hip_fp16.h>
#include <cstdint>
#include <cstddef>

// Problem constants
#define NB 4
#define C 128
#define P 4096      // HR*WR
#define S 64
#define Q 4096      // HS*WS
#define WS_DIM 64
#define HS_DIM 64

// fs_t stored pixel-major fp16 with PADR guard rows each side so unclamped
// corner rows (w=0 for OOB) can be fetched safely: rows accessed are
// qb + {0,1,64,65}, qb in [-65, 4095] -> padded row index in [15, 4240].
#define PADR  80
#define NROWS 4256   // 4096 + 2*PADR

// direct-to-LDS 16B gather (per-lane global addr, wave-linear LDS dest)
__device__ __forceinline__ void gload_lds16(const void* g, void* l) {
  __builtin_amdgcn_global_load_lds(
      (const __attribute__((address_space(1))) unsigned int*)g,
      (__attribute__((address_space(3))) unsigned int*)l, 16, 0, 0);
}

// per-batch transpose (128 x 4096) fp32 -> (4096 x 128) fp16, padded layout.
__global__ __launch_bounds__(256) void transpose_fs_h(
    const float* __restrict__ fs, __half* __restrict__ ws) {
  __shared__ float tile[32][65];
  int b = blockIdx.x;          // [0,1024)
  int n  = b >> 8;             // 256 tiles per batch
  int t  = b & 255;
  int rti = t & 3;             // 4 row-tiles of 32 channels
  int cti = t >> 2;            // 64 col-tiles of 64 pixels
  int r0 = rti << 5, c0 = cti << 6;
  const float* Sp = fs + (size_t)n * C * P;
  __half*      Dp = ws + (size_t)n * NROWS * C + (size_t)PADR * C;
  int tx = threadIdx.x & 15, ty = threadIdx.x >> 4;   // 16 x 16
#pragma unroll
  for (int i = 0; i < 2; ++i) {
    int row = ty + 16 * i;
    float4 v = *reinterpret_cast<const float4*>(
        &Sp[(size_t)(r0 + row) * P + c0 + tx * 4]);
    tile[row][tx * 4 + 0] = v.x;
    tile[row][tx * 4 + 1] = v.y;
    tile[row][tx * 4 + 2] = v.z;
    tile[row][tx * 4 + 3] = v.w;
  }
  __syncthreads();
  int ox = threadIdx.x & 7, oy = threadIdx.x >> 3;    // 8 x 32
#pragma unroll
  for (int i = 0; i < 2; ++i) {
    int prow = oy + 32 * i;
    __half2 h01 = __floats2half2_rn(tile[ox * 4 + 0][prow], tile[ox * 4 + 1][prow]);
    __half2 h23 = __floats2half2_rn(tile[ox * 4 + 2][prow], tile[ox * 4 + 3][prow]);
    uint2 pk;
    pk.x = *reinterpret_cast<unsigned int*>(&h01);
    pk.y = *reinterpret_cast<unsigned int*>(&h23);
    *reinterpret_cast<uint2*>(&Dp[(size_t)(c0 + prow) * C + r0 + ox * 4]) = pk;
  }
}

// One wave per (n, p); 4 waves/block = 4 consecutive p.
// Phase 1: thread t -> (s=t>>2, po=t&3): bilinear weights + UNCLAMPED pair
//          base qb = y0*64+x0 (guard rows make fetches safe; OOB corners have
//          w=0 exactly as the reference).
// Phase 2: 8 lanes per sample; each sample = TWO contiguous 512B segments
//          (rows x0,x0+1 for y0 and y0+1). Each glds instr = 8 samples x
//          128B contiguous runs (was 16 x 64B scattered) -> probes whether
//          the vector-path wall is request-granularity (128B) or bytes.
__global__ __launch_bounds__(256) void corr_main(
    const __half* __restrict__ ws, const float* __restrict__ fr_g,
    const float* __restrict__ grids, const float* __restrict__ mask,
    float* __restrict__ out, float* __restrict__ cmo) {
  __shared__ __align__(16) unsigned char stg[4][16384];
  __shared__ int    s_qb[4][68];
  __shared__ float4 s_w[4][65];
  __shared__ float  s_cmm[4][68];
  __shared__ float  s_out[4][68];
  __shared__ float  fr_lds[4][132];

  int b    = blockIdx.x;
  // XCD-aware swizzle: xcd = b&7; each XCD sees one batch n (fs fits its L2).
  int xcd  = b & 7;
  int n    = xcd >> 1;
  int half = xcd & 1;
  int grp  = b >> 3;                  // [0,512)
  int wv   = threadIdx.x >> 6;
  int lane = threadIdx.x & 63;
  int t    = threadIdx.x;
  int p_base = ((half << 9) + grp) << 2;   // 4*(half*512+grp) in [0,4096)

  // ---------------- phase 0: stage fr (fp32) for the block's 4 pixels --------
#pragma unroll
  for (int i = 0; i < 2; ++i) {
    int e  = t + 256 * i;          // [0,512)
    int c  = e >> 2;
    int po = e & 3;
    fr_lds[po][c] = fr_g[((size_t)n * C + c) * P + p_base + po];
  }

  // ---------------- phase 1: thread t -> (s, po) ----------------
  {
    int s  = t >> 2;
    int po = t & 3;
    int pp = p_base + po;
    float gx = grids[(((size_t)n * S + s) * 2 + 0) * P + pp];
    float gy = grids[(((size_t)n * S + s) * 2 + 1) * P + pp];
    float mval = mask[((size_t)n * S + s) * P + pp];
    float ix = gx - 0.5f, iy = gy - 0.5f;
    float x0f = floorf(ix), y0f = floorf(iy);
    float wx1 = ix - x0f, wy1 = iy - y0f;
    float wx0 = 1.0f - wx1, wy0 = 1.0f - wy1;
    int x0 = (int)x0f, y0 = (int)y0f;
    bool bx0 = (x0 >= 0) & (x0 < WS_DIM);
    bool bx1 = (x0 >= -1) & (x0 < WS_DIM - 1);   // x0+1 in bounds
    bool by0 = (y0 >= 0) & (y0 < HS_DIM);
    bool by1 = (y0 >= -1) & (y0 < HS_DIM - 1);   // y0+1 in bounds
    float w00 = (bx0 & by0) ? wx0 * wy0 : 0.0f;  // (x0 , y0 )
    float w01 = (bx0 & by1) ? wx0 * wy1 : 0.0f;  // (x0 , y0+1)
    float w10 = (bx1 & by0) ? wx1 * wy0 : 0.0f;  // (x0+1, y0 )
    float w11 = (bx1 & by1) ? wx1 * wy1 : 0.0f;  // (x0+1, y0+1)
    float msum = ((w00 + w01) + w10) + w11;      // reference order
    float cm  = (msum < 0.9999f) ? 0.0f : 1.0f;
    float cmm = cm * mval;
    int qb = y0 * WS_DIM + x0;                   // unclamped pair base
    qb = max(-PADR, min(qb, 4110));              // address-safety only
    s_qb[po][s]  = qb;
    s_w[po][s]   = make_float4(w00, w10, w01, w11);  // (A0,B0,A1,B1)
    s_cmm[po][s] = cmm;
    cmo[((size_t)n * S + s) * P + pp] = cmm;
  }
  __syncthreads();

  // ---------------- phase 2 ----------------
  int o  = lane & 7;    // 8 lanes per sample: lane o covers ch {o*8..+8} and
  int sl = lane >> 3;   //   {64+o*8..+8} of both x-rows; 8 samples per half
  float fr0[8], fr1[8];
  {
    float4 a = *reinterpret_cast<const float4*>(&fr_lds[wv][o * 8]);
    float4 bq = *reinterpret_cast<const float4*>(&fr_lds[wv][o * 8 + 4]);
    fr0[0] = a.x; fr0[1] = a.y; fr0[2] = a.z; fr0[3] = a.w;
    fr0[4] = bq.x; fr0[5] = bq.y; fr0[6] = bq.z; fr0[7] = bq.w;
    float4 c = *reinterpret_cast<const float4*>(&fr_lds[wv][64 + o * 8]);
    float4 d = *reinterpret_cast<const float4*>(&fr_lds[wv][64 + o * 8 + 4]);
    fr1[0] = c.x; fr1[1] = c.y; fr1[2] = c.z; fr1[3] = c.w;
    fr1[4] = d.x; fr1[5] = d.y; fr1[6] = d.z; fr1[7] = d.w;
  }
  const __half* fsn = ws + (size_t)n * NROWS * C + (size_t)PADR * C;
  unsigned char* mystg = &stg[wv][0];

#pragma unroll 1
  for (int r = 0; r < 4; ++r) {
    // keep prior iter's ds_reads strictly before this iter's LDS overwrite
    __builtin_amdgcn_sched_barrier(0);
    // issue 16 gathers: h-half, y-pair, j-quarter (128B contiguous per octet)
#pragma unroll
    for (int h = 0; h < 2; ++h) {
      int s = r * 16 + h * 8 + sl;
      int qb = s_qb[wv][s];
#pragma unroll
      for (int y = 0; y < 2; ++y) {
        const __half* src = fsn + (long)(qb + y * 64) * C + o * 8;
#pragma unroll
        for (int j = 0; j < 4; ++j)
          gload_lds16(src + j * 64, mystg + ((h * 2 + y) * 4 + j) * 1024);
      }
    }

#pragma unroll
    for (int h = 0; h < 2; ++h) {
      if (h == 0) { asm volatile("s_waitcnt vmcnt(8)" ::: "memory"); }
      else        { asm volatile("s_waitcnt vmcnt(0)" ::: "memory"); }
      int s = r * 16 + h * 8 + sl;
      float4 w4  = s_w[wv][s];
      float  cms = s_cmm[wv][s];
      float acc = 0.0f;
#pragma unroll
      for (int y = 0; y < 2; ++y) {
        const unsigned char* base = mystg + ((h * 2 + y) * 4) * 1024 + lane * 16;
        const __half2* b0 = reinterpret_cast<const __half2*>(base);          // x0 lo
        const __half2* b1 = reinterpret_cast<const __half2*>(base + 1024);   // x0 hi
        const __half2* b2 = reinterpret_cast<const __half2*>(base + 2048);   // x1 lo
        const __half2* b3 = reinterpret_cast<const __half2*>(base + 3072);   // x1 hi
        float d0 = 0.0f, d1 = 0.0f;
#pragma unroll
        for (int i = 0; i < 4; ++i) {
          float2 f0 = __half22float2(b0[i]);
          float2 f1 = __half22float2(b1[i]);
          float2 f2 = __half22float2(b2[i]);
          float2 f3 = __half22float2(b3[i]);
          d0 = fmaf(fr0[2 * i], f0.x, d0);
          d0 = fmaf(fr0[2 * i + 1], f0.y, d0);
          d0 = fmaf(fr1[2 * i], f1.x, d0);
          d0 = fmaf(fr1[2 * i + 1], f1.y, d0);
          d1 = fmaf(fr0[2 * i], f2.x, d1);
          d1 = fmaf(fr0[2 * i + 1], f2.y, d1);
          d1 = fmaf(fr1[2 * i], f3.x, d1);
          d1 = fmaf(fr1[2 * i + 1], f3.y, d1);
        }
        float wA = (y == 0) ? w4.x : w4.z;
        float wB = (y == 0) ? w4.y : w4.w;
        acc = fmaf(wA, d0, acc);
        acc = fmaf(wB, d1, acc);
      }
      // reduce across the 8 lanes of the octet
      acc += __shfl_xor(acc, 1);
      acc += __shfl_xor(acc, 2);
      acc += __shfl_xor(acc, 4);
      if (o == 0) s_out[wv][s] = acc * cms;
    }
  }
  __syncthreads();
  {
    int s = t >> 2, w2 = t & 3;
    out[((size_t)n * S + s) * P + (p_base + w2)] = s_out[w2][s];
  }
}

extern "C" void kernel_launch(void* const* d_in, const int* in_sizes, int n_in,
                              void* d_out, int out_size, void* d_ws, size_t ws_size,
                              hipStream_t stream) {
  const float* feat_ref = (const float*)d_in[0];  // (4,128,64,64)
  const float* feat_src = (const float*)d_in[1];  // (4,128,64,64)
  const float* grids    = (const float*)d_in[2];  // (4,64,2,64,64)
  const float* mask     = (const float*)d_in[3];  // (4,64,64,64)
  __half* ws = (__half*)d_ws;                     // needs 4*4256*128*2B = 4.4MB
  float* out = (float*)d_out;                     // out: 1,048,576 floats
  float* cmo = out + (size_t)NB * S * P;          // then corr_mask

  transpose_fs_h<<<1024, 256, 0, stream>>>(feat_src, ws);
  corr_main<<<4096, 256, 0, stream>>>(ws, feat_ref, grids, mask, out, cmo);
}